// Round 1
// baseline (888.549 us; speedup 1.0000x reference)
//
#include <hip/hip_runtime.h>
#include <hip/hip_bf16.h>
#include <stdint.h>

#define HDIM 128

typedef __attribute__((ext_vector_type(8))) short short8;
typedef __attribute__((ext_vector_type(4))) float f32x4;

__device__ __forceinline__ ushort f2bf(float f) {
  uint u = __float_as_uint(f);
  u = (u + 0x7fffu + ((u >> 16) & 1u)) >> 16;
  return (ushort)u;
}
__device__ __forceinline__ float bflo(uint v) { return __uint_as_float(v << 16); }
__device__ __forceinline__ float bfhi(uint v) { return __uint_as_float(v & 0xffff0000u); }

// ---------------- setup kernels ----------------

__global__ __launch_bounds__(256) void count_kernel(const int* __restrict__ ei,
                                                    int* __restrict__ cnt, int E) {
  int i = blockIdx.x * 256 + threadIdx.x;
  if (i < E) atomicAdd(&cnt[ei[E + i]], 1);  // dst row of edge_index
}

__global__ __launch_bounds__(256) void dis_kernel(const int* __restrict__ cnt,
                                                  float* __restrict__ dis, int N) {
  int i = blockIdx.x * 256 + threadIdx.x;
  if (i < N) dis[i] = rsqrtf((float)(cnt[i] + 1));  // +1 self loop, deg>=1 always
}

// per-block totals of v[n]=cnt[n]+1 over 1024-elem tiles
__global__ __launch_bounds__(256) void scan1(const int* __restrict__ cnt,
                                             int* __restrict__ bsum, int N) {
  __shared__ int red[256];
  int b = blockIdx.x, t = threadIdx.x;
  int base = b * 1024;
  int s = 0;
  for (int i = t; i < 1024; i += 256) {
    int n = base + i;
    if (n < N) s += cnt[n] + 1;
  }
  red[t] = s;
  __syncthreads();
  for (int off = 128; off; off >>= 1) {
    if (t < off) red[t] += red[t + off];
    __syncthreads();
  }
  if (t == 0) bsum[b] = red[0];
}

// exclusive scan of nb block sums (nb <= 256)
__global__ __launch_bounds__(256) void scan2(int* __restrict__ bsum, int nb) {
  __shared__ int sh[256];
  int t = threadIdx.x;
  int v = (t < nb) ? bsum[t] : 0;
  sh[t] = v;
  __syncthreads();
  for (int off = 1; off < 256; off <<= 1) {
    int add = (t >= off) ? sh[t - off] : 0;
    __syncthreads();
    sh[t] += add;
    __syncthreads();
  }
  if (t < nb) bsum[t] = sh[t] - v;
}

// per-element exclusive prefix -> row_ptr (N+1 entries) and cursor copy
__global__ __launch_bounds__(256) void scan3(const int* __restrict__ cnt,
                                             const int* __restrict__ bsum,
                                             int* __restrict__ rowptr,
                                             int* __restrict__ cursor, int N) {
  __shared__ int sh[256];
  int b = blockIdx.x, t = threadIdx.x;
  int base = b * 1024 + t * 4;
  int v[4];
#pragma unroll
  for (int i = 0; i < 4; ++i) {
    int n = base + i;
    v[i] = (n < N) ? cnt[n] + 1 : 0;
  }
  int tsum = v[0] + v[1] + v[2] + v[3];
  sh[t] = tsum;
  __syncthreads();
  for (int off = 1; off < 256; off <<= 1) {
    int add = (t >= off) ? sh[t - off] : 0;
    __syncthreads();
    sh[t] += add;
    __syncthreads();
  }
  int p = sh[t] - tsum + bsum[b];
#pragma unroll
  for (int i = 0; i < 4; ++i) {
    int n = base + i;
    if (n <= N) rowptr[n] = p;
    if (n < N) cursor[n] = p;
    p += v[i];
  }
}

__global__ __launch_bounds__(256) void fill_csr(const int* __restrict__ ei,
                                                const float* __restrict__ dis,
                                                int* __restrict__ cursor,
                                                int2* __restrict__ colw, int E, int N) {
  int i = blockIdx.x * 256 + threadIdx.x;
  if (i < E) {
    int s = ei[i], d = ei[E + i];
    int pos = atomicAdd(&cursor[d], 1);
    colw[pos] = make_int2(s, __float_as_int(dis[s] * dis[d]));
  } else if (i < E + N) {
    int n = i - E;
    int pos = atomicAdd(&cursor[n], 1);
    colw[pos] = make_int2(n, __float_as_int(dis[n] * dis[n]));
  }
}

__global__ __launch_bounds__(256) void cvt_x(const float* __restrict__ x,
                                             ushort* __restrict__ xb, int total) {
  int i = (blockIdx.x * 256 + threadIdx.x) * 4;
  if (i < total) {
    float4 v = *(const float4*)(x + i);
    uint2 o;
    o.x = (uint)f2bf(v.x) | ((uint)f2bf(v.y) << 16);
    o.y = (uint)f2bf(v.z) | ((uint)f2bf(v.w) << 16);
    *(uint2*)(xb + i) = o;
  }
}

// Pre-swizzle Ws into MFMA B-fragment order per layer:
// entry ((c*4+kk)*64 + lane)*8 + j  = W[k][n], n=c*16+(lane&15), k=kk*32+(lane>>4)*8+j
__global__ __launch_bounds__(256) void swz_w(const float* __restrict__ Ws,
                                             ushort* __restrict__ Wsw, int total) {
  int idx = blockIdx.x * 256 + threadIdx.x;
  if (idx >= total) return;
  int l = idx >> 14, r = idx & 16383;
  int j = r & 7, lane = (r >> 3) & 63, kk = (r >> 9) & 3, c = r >> 11;
  int n = c * 16 + (lane & 15);
  int k = kk * 32 + (lane >> 4) * 8 + j;
  Wsw[idx] = f2bf(Ws[l * 16384 + k * HDIM + n]);
}

// ---------------- per-layer kernels ----------------

// XW = X @ W  (bf16 in/out, fp32 acc). 64 rows per block, 4 waves x 16 rows.
__global__ __launch_bounds__(256) void gemm_kernel(const ushort* __restrict__ X,
                                                   const ushort* __restrict__ Wsw,
                                                   ushort* __restrict__ XW, int N) {
  __shared__ ushort wlds[16384];  // 32 KB: swizzled W, later reused as C tile
  const int t = threadIdx.x;
  {
    const int4* src = (const int4*)Wsw;
    int4* dst = (int4*)wlds;
#pragma unroll
    for (int i = 0; i < 8; ++i) dst[t + 256 * i] = src[t + 256 * i];
  }
  __syncthreads();

  const int wave = t >> 6, lane = t & 63;
  const int kq = lane >> 4;  // 0..3
  const int row0 = blockIdx.x * 64 + wave * 16 + (lane & 15);
  const bool inb = row0 < N;

  short8 afr[4];
  const short8* arow = (const short8*)(X + (size_t)row0 * HDIM);
#pragma unroll
  for (int kk = 0; kk < 4; ++kk) {
    if (inb) afr[kk] = arow[kk * 4 + kq];
    else afr[kk] = short8{0, 0, 0, 0, 0, 0, 0, 0};
  }

  f32x4 acc[8];
#pragma unroll
  for (int c = 0; c < 8; ++c) acc[c] = f32x4{0.f, 0.f, 0.f, 0.f};

#pragma unroll
  for (int kk = 0; kk < 4; ++kk) {
#pragma unroll
    for (int c = 0; c < 8; ++c) {
      short8 bfr = *(const short8*)(wlds + (((c * 4 + kk) * 64 + lane) << 3));
      acc[c] = __builtin_amdgcn_mfma_f32_16x16x32_bf16(afr[kk], bfr, acc[c], 0, 0, 0);
    }
  }

  __syncthreads();  // done reading W; reuse LDS for C tile
  // C/D layout: col = lane&15, row = kq*4 + r
  const int m0 = wave * 16 + kq * 4;
#pragma unroll
  for (int c = 0; c < 8; ++c) {
    int col = c * 16 + (lane & 15);
#pragma unroll
    for (int r = 0; r < 4; ++r) wlds[(m0 + r) * HDIM + col] = f2bf(acc[c][r]);
  }
  __syncthreads();
  // coalesced store: 64 rows x 128 bf16 = 1024 int4
  const int4* csrc = (const int4*)wlds;
  int4* gdst = (int4*)XW;
#pragma unroll
  for (int i = 0; i < 4; ++i) {
    int idx = t + 256 * i;  // 16 int4 per row
    int row = blockIdx.x * 64 + (idx >> 4);
    if (row < N) gdst[(size_t)blockIdx.x * 1024 + idx] = csrc[idx];
  }
}

// x_out[n] = relu(bias + sum_j w_j * xw[col_j])  — one wave per node, lane = 2 columns
__global__ __launch_bounds__(256) void agg_kernel(const ushort* __restrict__ XW,
                                                  const int2* __restrict__ colw,
                                                  const int* __restrict__ rowptr,
                                                  const float* __restrict__ bias,
                                                  ushort* __restrict__ Xout, int N) {
  const int lane = threadIdx.x & 63;
  const int node = blockIdx.x * 4 + (threadIdx.x >> 6);
  if (node >= N) return;
  int beg = rowptr[node], end = rowptr[node + 1];
  float a0 = 0.f, a1 = 0.f;
  int j = beg;
  for (; j + 1 < end; j += 2) {
    int2 c0 = colw[j];
    int2 c1 = colw[j + 1];
    uint v0 = *(const uint*)(XW + (size_t)c0.x * HDIM + lane * 2);
    uint v1 = *(const uint*)(XW + (size_t)c1.x * HDIM + lane * 2);
    float w0 = __int_as_float(c0.y), w1 = __int_as_float(c1.y);
    a0 += w0 * bflo(v0) + w1 * bflo(v1);
    a1 += w0 * bfhi(v0) + w1 * bfhi(v1);
  }
  if (j < end) {
    int2 c0 = colw[j];
    uint v0 = *(const uint*)(XW + (size_t)c0.x * HDIM + lane * 2);
    float w0 = __int_as_float(c0.y);
    a0 += w0 * bflo(v0);
    a1 += w0 * bfhi(v0);
  }
  float2 bv = *(const float2*)(bias + lane * 2);
  a0 = fmaxf(a0 + bv.x, 0.f);
  a1 = fmaxf(a1 + bv.y, 0.f);
  uint pk = (uint)f2bf(a0) | ((uint)f2bf(a1) << 16);
  *(uint*)(Xout + (size_t)node * HDIM + lane * 2) = pk;
}

// ---------------- pooling + head ----------------

__global__ __launch_bounds__(256) void pool_partial(const ushort* __restrict__ x,
                                                    const int* __restrict__ batch,
                                                    float* __restrict__ pooled,
                                                    int* __restrict__ gcnt, int N) {
  const int g = blockIdx.x, s = blockIdx.y;  // gridDim.y = 8 splits
  const int t = threadIdx.x;
  __shared__ int range[2];
  __shared__ float sums[256];
  if (t < 2) {
    int target = g + t;
    int lo = 0, hi = N;
    while (lo < hi) {
      int mid = (lo + hi) >> 1;
      if (batch[mid] < target) lo = mid + 1;
      else hi = mid;
    }
    range[t] = lo;
  }
  __syncthreads();
  int beg = range[0], end = range[1];
  if (s == 0 && t == 0) gcnt[g] = end - beg;
  int col = t & 127, half = t >> 7;
  float acc = 0.f;
  for (int n = beg + s * 2 + half; n < end; n += 16) {
    acc += bflo((uint)x[(size_t)n * HDIM + col] << 0) * 0.f +
           __uint_as_float(((uint)x[(size_t)n * HDIM + col]) << 16);
  }
  sums[t] = acc;
  __syncthreads();
  if (t < 128) atomicAdd(&pooled[g * HDIM + t], sums[t] + sums[t + 128]);
}

__global__ __launch_bounds__(256) void out_final(const float* __restrict__ pooled,
                                                 const int* __restrict__ gcnt,
                                                 const float* __restrict__ W_out,
                                                 const float* __restrict__ b_out,
                                                 float* __restrict__ out, int G, int C) {
  int i = blockIdx.x * 256 + threadIdx.x;
  if (i >= G * C) return;
  int g = i / C, c = i - g * C;
  float inv = 1.f / (float)max(gcnt[g], 1);
  const float* pg = pooled + g * HDIM;
  float o = 0.f;
  for (int h = 0; h < HDIM; ++h) o += pg[h] * W_out[h * C + c];
  out[i] = b_out[c] + o * inv;
}

// ---------------- host ----------------

extern "C" void kernel_launch(void* const* d_in, const int* in_sizes, int n_in,
                              void* d_out, int out_size, void* d_ws, size_t ws_size,
                              hipStream_t stream) {
  (void)n_in;
  (void)ws_size;
  const float* x = (const float*)d_in[0];
  const int* ei = (const int*)d_in[1];
  const int* batch = (const int*)d_in[2];
  const float* Ws = (const float*)d_in[4];
  const float* bs = (const float*)d_in[5];
  const float* W_out = (const float*)d_in[6];
  const float* b_out = (const float*)d_in[7];
  float* out = (float*)d_out;

  const int N = in_sizes[0] / HDIM;
  const int E = in_sizes[1] / 2;
  const int L = in_sizes[5] / HDIM;
  const int C = in_sizes[7];
  const int G = out_size / C;

  char* p = (char*)d_ws;
  auto carve = [&](size_t bytes) {
    char* r = p;
    p += (bytes + 255) & ~(size_t)255;
    return r;
  };
  int* cnt = (int*)carve((size_t)N * 4);
  float* dis = (float*)carve((size_t)N * 4);
  int* rowptr = (int*)carve((size_t)(N + 1) * 4);
  int* cursor = (int*)carve((size_t)N * 4);
  int* bsum = (int*)carve(4096);
  int2* colw = (int2*)carve((size_t)(E + N) * 8);
  ushort* Wsw = (ushort*)carve((size_t)L * HDIM * HDIM * 2);
  ushort* xw = (ushort*)carve((size_t)N * HDIM * 2);
  ushort* xa = (ushort*)carve((size_t)N * HDIM * 2);
  ushort* xb = (ushort*)carve((size_t)N * HDIM * 2);
  float* pooled = (float*)carve((size_t)G * HDIM * 4 + (size_t)G * 4);
  int* gcnt = (int*)(pooled + (size_t)G * HDIM);

  hipMemsetAsync(cnt, 0, (size_t)N * 4, stream);
  hipMemsetAsync(pooled, 0, (size_t)G * HDIM * 4 + (size_t)G * 4, stream);

  count_kernel<<<(E + 255) / 256, 256, 0, stream>>>(ei, cnt, E);
  dis_kernel<<<(N + 255) / 256, 256, 0, stream>>>(cnt, dis, N);
  int nb = (N + 1 + 1023) / 1024;
  scan1<<<nb, 256, 0, stream>>>(cnt, bsum, N);
  scan2<<<1, 256, 0, stream>>>(bsum, nb);
  scan3<<<nb, 256, 0, stream>>>(cnt, bsum, rowptr, cursor, N);
  fill_csr<<<(E + N + 255) / 256, 256, 0, stream>>>(ei, dis, cursor, colw, E, N);
  cvt_x<<<((N * HDIM / 4) + 255) / 256, 256, 0, stream>>>(x, xa, N * HDIM);
  swz_w<<<(L * HDIM * HDIM + 255) / 256, 256, 0, stream>>>(Ws, Wsw, L * HDIM * HDIM);

  ushort* xc = xa;
  ushort* xn = xb;
  for (int l = 0; l < L; ++l) {
    gemm_kernel<<<(N + 63) / 64, 256, 0, stream>>>(xc, Wsw + (size_t)l * HDIM * HDIM, xw, N);
    agg_kernel<<<(N + 3) / 4, 256, 0, stream>>>(xw, colw, rowptr, bs + (size_t)l * HDIM, xn, N);
    ushort* tmp = xc;
    xc = xn;
    xn = tmp;
  }
  pool_partial<<<dim3(G, 8), 256, 0, stream>>>(xc, batch, pooled, gcnt, N);
  out_final<<<(G * C + 255) / 256, 256, 0, stream>>>(pooled, gcnt, W_out, b_out, out, G, C);
}

// Round 2
// 759.438 us; speedup vs baseline: 1.1700x; 1.1700x over previous
//
#include <hip/hip_runtime.h>
#include <hip/hip_bf16.h>
#include <stdint.h>

#define HDIM 128

typedef __attribute__((ext_vector_type(8))) short short8;
typedef __attribute__((ext_vector_type(4))) float f32x4;

__device__ __forceinline__ ushort f2bf(float f) {
  uint u = __float_as_uint(f);
  u = (u + 0x7fffu + ((u >> 16) & 1u)) >> 16;
  return (ushort)u;
}
__device__ __forceinline__ float bflo(uint v) { return __uint_as_float(v << 16); }
__device__ __forceinline__ float bfhi(uint v) { return __uint_as_float(v & 0xffff0000u); }

// ---------------- setup kernels ----------------

__global__ __launch_bounds__(256) void count_kernel(const int* __restrict__ ei,
                                                    int* __restrict__ cnt, int E) {
  int i = blockIdx.x * 256 + threadIdx.x;
  if (i < E) atomicAdd(&cnt[ei[E + i]], 1);  // dst row of edge_index
}

__global__ __launch_bounds__(256) void dis_kernel(const int* __restrict__ cnt,
                                                  float* __restrict__ dis, int N) {
  int i = blockIdx.x * 256 + threadIdx.x;
  if (i < N) dis[i] = rsqrtf((float)(cnt[i] + 1));  // +1 self loop, deg>=1 always
}

// per-block totals of v[n]=cnt[n]+1 over 1024-elem tiles
__global__ __launch_bounds__(256) void scan1(const int* __restrict__ cnt,
                                             int* __restrict__ bsum, int N) {
  __shared__ int red[256];
  int b = blockIdx.x, t = threadIdx.x;
  int base = b * 1024;
  int s = 0;
  for (int i = t; i < 1024; i += 256) {
    int n = base + i;
    if (n < N) s += cnt[n] + 1;
  }
  red[t] = s;
  __syncthreads();
  for (int off = 128; off; off >>= 1) {
    if (t < off) red[t] += red[t + off];
    __syncthreads();
  }
  if (t == 0) bsum[b] = red[0];
}

// exclusive scan of nb block sums (nb <= 256)
__global__ __launch_bounds__(256) void scan2(int* __restrict__ bsum, int nb) {
  __shared__ int sh[256];
  int t = threadIdx.x;
  int v = (t < nb) ? bsum[t] : 0;
  sh[t] = v;
  __syncthreads();
  for (int off = 1; off < 256; off <<= 1) {
    int add = (t >= off) ? sh[t - off] : 0;
    __syncthreads();
    sh[t] += add;
    __syncthreads();
  }
  if (t < nb) bsum[t] = sh[t] - v;
}

// per-element exclusive prefix -> row_ptr (N+1 entries) and cursor copy
__global__ __launch_bounds__(256) void scan3(const int* __restrict__ cnt,
                                             const int* __restrict__ bsum,
                                             int* __restrict__ rowptr,
                                             int* __restrict__ cursor, int N) {
  __shared__ int sh[256];
  int b = blockIdx.x, t = threadIdx.x;
  int base = b * 1024 + t * 4;
  int v[4];
#pragma unroll
  for (int i = 0; i < 4; ++i) {
    int n = base + i;
    v[i] = (n < N) ? cnt[n] + 1 : 0;
  }
  int tsum = v[0] + v[1] + v[2] + v[3];
  sh[t] = tsum;
  __syncthreads();
  for (int off = 1; off < 256; off <<= 1) {
    int add = (t >= off) ? sh[t - off] : 0;
    __syncthreads();
    sh[t] += add;
    __syncthreads();
  }
  int p = sh[t] - tsum + bsum[b];
#pragma unroll
  for (int i = 0; i < 4; ++i) {
    int n = base + i;
    if (n <= N) rowptr[n] = p;
    if (n < N) cursor[n] = p;
    p += v[i];
  }
}

__global__ __launch_bounds__(256) void fill_csr(const int* __restrict__ ei,
                                                const float* __restrict__ dis,
                                                int* __restrict__ cursor,
                                                int2* __restrict__ colw, int E, int N) {
  int i = blockIdx.x * 256 + threadIdx.x;
  if (i < E) {
    int s = ei[i], d = ei[E + i];
    int pos = atomicAdd(&cursor[d], 1);
    colw[pos] = make_int2(s, __float_as_int(dis[s] * dis[d]));
  } else if (i < E + N) {
    int n = i - E;
    int pos = atomicAdd(&cursor[n], 1);
    colw[pos] = make_int2(n, __float_as_int(dis[n] * dis[n]));
  }
}

// Pre-swizzle Ws into MFMA B-fragment order per layer:
// entry ((c*4+kk)*64 + lane)*8 + j  = W[k][n], n=c*16+(lane&15), k=kk*32+(lane>>4)*8+j
__global__ __launch_bounds__(256) void swz_w(const float* __restrict__ Ws,
                                             ushort* __restrict__ Wsw, int total) {
  int idx = blockIdx.x * 256 + threadIdx.x;
  if (idx >= total) return;
  int l = idx >> 14, r = idx & 16383;
  int j = r & 7, lane = (r >> 3) & 63, kk = (r >> 9) & 3, c = r >> 11;
  int n = c * 16 + (lane & 15);
  int k = kk * 32 + (lane >> 4) * 8 + j;
  Wsw[idx] = f2bf(Ws[l * 16384 + k * HDIM + n]);
}

// ---------------- per-layer kernels ----------------

// XW = X @ W  (fp32 or bf16 in, bf16 out, fp32 acc). 64 rows/block, 4 waves x 16 rows.
template <bool F32IN>
__global__ __launch_bounds__(256) void gemm_kernel(const void* __restrict__ Xin,
                                                   const ushort* __restrict__ Wsw,
                                                   ushort* __restrict__ XW, int N) {
  __shared__ ushort wlds[16384];  // 32 KB: swizzled W, later reused as C tile
  const int t = threadIdx.x;
  {
    const int4* src = (const int4*)Wsw;
    int4* dst = (int4*)wlds;
#pragma unroll
    for (int i = 0; i < 8; ++i) dst[t + 256 * i] = src[t + 256 * i];
  }
  __syncthreads();

  const int wave = t >> 6, lane = t & 63;
  const int kq = lane >> 4;  // 0..3
  const int row0 = blockIdx.x * 64 + wave * 16 + (lane & 15);
  const bool inb = row0 < N;

  short8 afr[4];
#pragma unroll
  for (int kk = 0; kk < 4; ++kk) afr[kk] = short8{0, 0, 0, 0, 0, 0, 0, 0};
  if (inb) {
    if constexpr (F32IN) {
      const float* arow = (const float*)Xin + (size_t)row0 * HDIM;
#pragma unroll
      for (int kk = 0; kk < 4; ++kk) {
        float4 x0 = *(const float4*)(arow + kk * 32 + kq * 8);
        float4 x1 = *(const float4*)(arow + kk * 32 + kq * 8 + 4);
        short8 f;
        f[0] = (short)f2bf(x0.x); f[1] = (short)f2bf(x0.y);
        f[2] = (short)f2bf(x0.z); f[3] = (short)f2bf(x0.w);
        f[4] = (short)f2bf(x1.x); f[5] = (short)f2bf(x1.y);
        f[6] = (short)f2bf(x1.z); f[7] = (short)f2bf(x1.w);
        afr[kk] = f;
      }
    } else {
      const short8* arow = (const short8*)((const ushort*)Xin + (size_t)row0 * HDIM);
#pragma unroll
      for (int kk = 0; kk < 4; ++kk) afr[kk] = arow[kk * 4 + kq];
    }
  }

  f32x4 acc[8];
#pragma unroll
  for (int c = 0; c < 8; ++c) acc[c] = f32x4{0.f, 0.f, 0.f, 0.f};

#pragma unroll
  for (int kk = 0; kk < 4; ++kk) {
#pragma unroll
    for (int c = 0; c < 8; ++c) {
      short8 bfr = *(const short8*)(wlds + (((c * 4 + kk) * 64 + lane) << 3));
      acc[c] = __builtin_amdgcn_mfma_f32_16x16x32_bf16(afr[kk], bfr, acc[c], 0, 0, 0);
    }
  }

  __syncthreads();  // done reading W; reuse LDS for C tile
  // C/D layout: col = lane&15, row = kq*4 + r
  const int m0 = wave * 16 + kq * 4;
#pragma unroll
  for (int c = 0; c < 8; ++c) {
    int col = c * 16 + (lane & 15);
#pragma unroll
    for (int r = 0; r < 4; ++r) wlds[(m0 + r) * HDIM + col] = f2bf(acc[c][r]);
  }
  __syncthreads();
  // coalesced store: 64 rows x 128 bf16 = 1024 int4
  const int4* csrc = (const int4*)wlds;
  int4* gdst = (int4*)XW;
#pragma unroll
  for (int i = 0; i < 4; ++i) {
    int idx = t + 256 * i;  // 16 int4 per row
    int row = blockIdx.x * 64 + (idx >> 4);
    if (row < N) gdst[(size_t)blockIdx.x * 1024 + idx] = csrc[idx];
  }
}

// load 8 colw entries [j, j+8) clamped to end-1; weight zeroed for padded slots
__device__ __forceinline__ void ldc8(const int2* __restrict__ colw, int j, int end,
                                     int2 c[8]) {
#pragma unroll
  for (int k = 0; k < 8; ++k) {
    int idx = j + k;
    int2 v = colw[idx < end ? idx : end - 1];
    if (idx >= end) v.y = 0;
    c[k] = v;
  }
}

// x_out[n] = relu(bias + sum_j w_j * xw[col_j]) — one wave per node, lane = 2 columns.
// 8-edge chunks: 8 independent gathers outstanding + next chunk's colw prefetched.
__global__ __launch_bounds__(256) void agg_kernel(const ushort* __restrict__ XW,
                                                  const int2* __restrict__ colw,
                                                  const int* __restrict__ rowptr,
                                                  const float* __restrict__ bias,
                                                  ushort* __restrict__ Xout, int N) {
  const int lane = threadIdx.x & 63;
  const int node = blockIdx.x * 4 + (threadIdx.x >> 6);
  if (node >= N) return;
  const int beg = rowptr[node], end = rowptr[node + 1];
  const ushort* xwl = XW + lane * 2;

  int2 c[8];
  ldc8(colw, beg, end, c);
  float a0 = 0.f, a1 = 0.f, b0 = 0.f, b1 = 0.f;
  int j = beg;
  while (j < end) {
    uint v[8];
#pragma unroll
    for (int k = 0; k < 8; ++k)
      v[k] = *(const uint*)(xwl + (size_t)c[k].x * HDIM);
    const int jn = j + 8;
    const bool more = jn < end;
    int2 cn[8];
    if (more) ldc8(colw, jn, end, cn);  // issued while gathers are in flight
#pragma unroll
    for (int k = 0; k < 8; k += 2) {
      float w0 = __int_as_float(c[k].y), w1 = __int_as_float(c[k + 1].y);
      a0 += w0 * bflo(v[k]);
      a1 += w0 * bfhi(v[k]);
      b0 += w1 * bflo(v[k + 1]);
      b1 += w1 * bfhi(v[k + 1]);
    }
    if (more) {
#pragma unroll
      for (int k = 0; k < 8; ++k) c[k] = cn[k];
    }
    j = jn;
  }
  float2 bv = *(const float2*)(bias + lane * 2);
  float r0 = fmaxf(a0 + b0 + bv.x, 0.f);
  float r1 = fmaxf(a1 + b1 + bv.y, 0.f);
  uint pk = (uint)f2bf(r0) | ((uint)f2bf(r1) << 16);
  *(uint*)(Xout + (size_t)node * HDIM + lane * 2) = pk;
}

// ---------------- pooling + head ----------------

__global__ __launch_bounds__(256) void pool_partial(const ushort* __restrict__ x,
                                                    const int* __restrict__ batch,
                                                    float* __restrict__ pooled,
                                                    int* __restrict__ gcnt, int N) {
  const int g = blockIdx.x, s = blockIdx.y;  // gridDim.y = 8 splits
  const int t = threadIdx.x;
  __shared__ int range[2];
  __shared__ float sums[256];
  if (t < 2) {
    int target = g + t;
    int lo = 0, hi = N;
    while (lo < hi) {
      int mid = (lo + hi) >> 1;
      if (batch[mid] < target) lo = mid + 1;
      else hi = mid;
    }
    range[t] = lo;
  }
  __syncthreads();
  int beg = range[0], end = range[1];
  if (s == 0 && t == 0) gcnt[g] = end - beg;
  int col = t & 127, half = t >> 7;
  float acc = 0.f;
  for (int n = beg + s * 2 + half; n < end; n += 16) {
    acc += __uint_as_float(((uint)x[(size_t)n * HDIM + col]) << 16);
  }
  sums[t] = acc;
  __syncthreads();
  if (t < 128) atomicAdd(&pooled[g * HDIM + t], sums[t] + sums[t + 128]);
}

__global__ __launch_bounds__(256) void out_final(const float* __restrict__ pooled,
                                                 const int* __restrict__ gcnt,
                                                 const float* __restrict__ W_out,
                                                 const float* __restrict__ b_out,
                                                 float* __restrict__ out, int G, int C) {
  int i = blockIdx.x * 256 + threadIdx.x;
  if (i >= G * C) return;
  int g = i / C, c = i - g * C;
  float inv = 1.f / (float)max(gcnt[g], 1);
  const float* pg = pooled + g * HDIM;
  float o = 0.f;
  for (int h = 0; h < HDIM; ++h) o += pg[h] * W_out[h * C + c];
  out[i] = b_out[c] + o * inv;
}

// ---------------- host ----------------

extern "C" void kernel_launch(void* const* d_in, const int* in_sizes, int n_in,
                              void* d_out, int out_size, void* d_ws, size_t ws_size,
                              hipStream_t stream) {
  (void)n_in;
  (void)ws_size;
  const float* x = (const float*)d_in[0];
  const int* ei = (const int*)d_in[1];
  const int* batch = (const int*)d_in[2];
  const float* Ws = (const float*)d_in[4];
  const float* bs = (const float*)d_in[5];
  const float* W_out = (const float*)d_in[6];
  const float* b_out = (const float*)d_in[7];
  float* out = (float*)d_out;

  const int N = in_sizes[0] / HDIM;
  const int E = in_sizes[1] / 2;
  const int L = in_sizes[5] / HDIM;
  const int C = in_sizes[7];
  const int G = out_size / C;

  char* p = (char*)d_ws;
  auto carve = [&](size_t bytes) {
    char* r = p;
    p += (bytes + 255) & ~(size_t)255;
    return r;
  };
  int* cnt = (int*)carve((size_t)N * 4);
  float* dis = (float*)carve((size_t)N * 4);
  int* rowptr = (int*)carve((size_t)(N + 1) * 4);
  int* cursor = (int*)carve((size_t)N * 4);
  int* bsum = (int*)carve(4096);
  int2* colw = (int2*)carve((size_t)(E + N) * 8);
  ushort* Wsw = (ushort*)carve((size_t)L * HDIM * HDIM * 2);
  ushort* xw = (ushort*)carve((size_t)N * HDIM * 2);
  ushort* y0 = (ushort*)carve((size_t)N * HDIM * 2);
  ushort* y1 = (ushort*)carve((size_t)N * HDIM * 2);
  float* pooled = (float*)carve((size_t)G * HDIM * 4 + (size_t)G * 4);
  int* gcnt = (int*)(pooled + (size_t)G * HDIM);

  hipMemsetAsync(cnt, 0, (size_t)N * 4, stream);
  hipMemsetAsync(pooled, 0, (size_t)G * HDIM * 4 + (size_t)G * 4, stream);

  count_kernel<<<(E + 255) / 256, 256, 0, stream>>>(ei, cnt, E);
  dis_kernel<<<(N + 255) / 256, 256, 0, stream>>>(cnt, dis, N);
  int nb = (N + 1 + 1023) / 1024;
  scan1<<<nb, 256, 0, stream>>>(cnt, bsum, N);
  scan2<<<1, 256, 0, stream>>>(bsum, nb);
  scan3<<<nb, 256, 0, stream>>>(cnt, bsum, rowptr, cursor, N);
  fill_csr<<<(E + N + 255) / 256, 256, 0, stream>>>(ei, dis, cursor, colw, E, N);
  swz_w<<<(L * HDIM * HDIM + 255) / 256, 256, 0, stream>>>(Ws, Wsw, L * HDIM * HDIM);

  const int gb = (N + 63) / 64;
  // layer 0: fp32 input fused into the GEMM (no separate cvt pass)
  gemm_kernel<true><<<gb, 256, 0, stream>>>(x, Wsw, xw, N);
  agg_kernel<<<(N + 3) / 4, 256, 0, stream>>>(xw, colw, rowptr, bs, y0, N);
  ushort* xc = y0;
  ushort* xn = y1;
  for (int l = 1; l < L; ++l) {
    gemm_kernel<false><<<gb, 256, 0, stream>>>(xc, Wsw + (size_t)l * HDIM * HDIM, xw, N);
    agg_kernel<<<(N + 3) / 4, 256, 0, stream>>>(xw, colw, rowptr, bs + (size_t)l * HDIM, xn, N);
    ushort* tmp = xc;
    xc = xn;
    xn = tmp;
  }
  pool_partial<<<dim3(G, 8), 256, 0, stream>>>(xc, batch, pooled, gcnt, N);
  out_final<<<(G * C + 255) / 256, 256, 0, stream>>>(pooled, gcnt, W_out, b_out, out, G, C);
}